// Round 1
// baseline (408.465 us; speedup 1.0000x reference)
//
#include <hip/hip_runtime.h>
#include <hip/hip_bf16.h>
#include <math.h>

#define KK 5
#define Bc 5.0f
#define NN 32768
#define DD 64
#define LL 63
#define PP 14
#define MIN_Wc 0.001f
#define MIN_Hc 0.001f
#define MIN_Dc 0.001f
#define LOG2E 1.44269504088896340736f
#define TWOLOG2E 2.88539008177792681472f
#define LN2 0.69314718055994530942f

typedef float f4 __attribute__((ext_vector_type(4)));
typedef float f32x4 __attribute__((ext_vector_type(4)));
typedef float f2 __attribute__((ext_vector_type(2)));
typedef short short8 __attribute__((ext_vector_type(8)));

__device__ __forceinline__ float rcp_fast(float v)   { return __builtin_amdgcn_rcpf(v); }
__device__ __forceinline__ float exp2_fast(float v)  { return __builtin_amdgcn_exp2f(v); }  // v_exp_f32: 2^x
__device__ __forceinline__ float log2_fast(float v)  { return __builtin_amdgcn_logf(v); }   // v_log_f32: log2
// input pre-scaled by 2*log2(e): tanh(x) = 1 - 2/(2^(2x*log2e)+1)
__device__ __forceinline__ float tanh_pre(float t2) {
    float e = exp2_fast(t2);
    return 1.0f - 2.0f * rcp_fast(e + 1.0f);
}
// input pre-scaled by log2(e): softplus(v) = ln2*log2(1+2^(v*log2e))
__device__ __forceinline__ float softplus2(float v2) {
    return (v2 > 21.7f) ? LN2 * v2 : LN2 * log2_fast(1.0f + exp2_fast(v2));
}
// truncating bf16 (1 shift); absmax margin ~3x covers the extra ulp
__device__ __forceinline__ ushort to_bf16t(float v) {
    return (ushort)(__float_as_uint(v) >> 16);
}
// pack two fp32 -> one u32 of two truncated bf16 (lo=v0, hi=v1)
__device__ __forceinline__ unsigned pack_bf16t2(float v0, float v1) {
    return (__float_as_uint(v0) >> 16) | (__float_as_uint(v1) & 0xFFFF0000u);
}
__device__ __forceinline__ float bflo(unsigned u) { return __uint_as_float(u << 16); }
__device__ __forceinline__ float bfhi(unsigned u) { return __uint_as_float(u & 0xFFFF0000u); }
__device__ __forceinline__ f2 splat2(float v) { f2 r; r.x = v; r.y = v; return r; }
__device__ __forceinline__ f4 splat4(float v) { f4 r; r.x = v; r.y = v; r.z = v; r.w = v; return r; }
__device__ __forceinline__ f4 exp2_q(f4 v) {
    f4 r; r.x = exp2_fast(v.x); r.y = exp2_fast(v.y); r.z = exp2_fast(v.z); r.w = exp2_fast(v.w); return r;
}
__device__ __forceinline__ f4 rcp_q(f4 v) {
    f4 r; r.x = rcp_fast(v.x); r.y = rcp_fast(v.y); r.z = rcp_fast(v.z); r.w = rcp_fast(v.w); return r;
}

__device__ __forceinline__ short8 pack_a(f4 v0, f4 v1) {
    short8 a;
    a[0] = (short)to_bf16t(v0.x); a[1] = (short)to_bf16t(v0.y);
    a[2] = (short)to_bf16t(v0.z); a[3] = (short)to_bf16t(v0.w);
    a[4] = (short)to_bf16t(v1.x); a[5] = (short)to_bf16t(v1.y);
    a[6] = (short)to_bf16t(v1.z); a[7] = (short)to_bf16t(v1.w);
    return a;
}

// per-dim LDS weight slot (floats, stride 216 = 864B, 16B-aligned):
// [0,64) 2log2e*W2[h][g]  [64,72) 2log2e*b2  [72,200) log2e*W3 padded [g][16]  [200,216) log2e*b3
#define WSL 216
#define H1S 72    // u16 row stride: 144B (proven residue, 0 measured conflicts)
#define BS  72    // Blds u16 row stride (same proven residue)

// ---- L2+L3 MLP for one dim, TWO samples; p out in log2 domain --------------
// (weights pre-scaled: W2/b2 by 2log2e, W3/b3 by log2e at staging time)
__device__ __forceinline__ void mlp2(
    const float* wp, uint4 hv0, uint4 hv1,
    f4& pa0, f4& pb0, f4& pc0, f4& pd0,
    f4& pa1, f4& pb1, f4& pc1, f4& pd1)
{
    float h0_0 = bflo(hv0.x), h1_0 = bflo(hv1.x);
    float h0_1 = bfhi(hv0.x), h1_1 = bfhi(hv1.x);
    float h0_2 = bflo(hv0.y), h1_2 = bflo(hv1.y);
    float h0_3 = bfhi(hv0.y), h1_3 = bfhi(hv1.y);
    float h0_4 = bflo(hv0.z), h1_4 = bflo(hv1.z);
    float h0_5 = bfhi(hv0.z), h1_5 = bfhi(hv1.z);
    float h0_6 = bflo(hv0.w), h1_6 = bflo(hv1.w);
    float h0_7 = bfhi(hv0.w), h1_7 = bfhi(hv1.w);

    f4 a0 = *(const f4*)(wp + 64), b0 = *(const f4*)(wp + 68);
    f4 a1 = a0, b1 = b0;
#define L2STEP(HI, X0, X1) { \
    f4 wa = *(const f4*)(wp + (HI) * 8); \
    f4 wb = *(const f4*)(wp + (HI) * 8 + 4); \
    f4 v0 = splat4(X0), v1 = splat4(X1); \
    a0 += v0 * wa; a1 += v1 * wa; \
    b0 += v0 * wb; b1 += v1 * wb; }
    L2STEP(0, h0_0, h1_0)
    L2STEP(1, h0_1, h1_1)
    L2STEP(2, h0_2, h1_2)
    L2STEP(3, h0_3, h1_3)
    L2STEP(4, h0_4, h1_4)
    L2STEP(5, h0_5, h1_5)
    L2STEP(6, h0_6, h1_6)
    L2STEP(7, h0_7, h1_7)
#undef L2STEP
    float g0_0 = tanh_pre(a0.x), g1_0 = tanh_pre(a1.x);
    float g0_1 = tanh_pre(a0.y), g1_1 = tanh_pre(a1.y);
    float g0_2 = tanh_pre(a0.z), g1_2 = tanh_pre(a1.z);
    float g0_3 = tanh_pre(a0.w), g1_3 = tanh_pre(a1.w);
    float g0_4 = tanh_pre(b0.x), g1_4 = tanh_pre(b1.x);
    float g0_5 = tanh_pre(b0.y), g1_5 = tanh_pre(b1.y);
    float g0_6 = tanh_pre(b0.z), g1_6 = tanh_pre(b1.z);
    float g0_7 = tanh_pre(b0.w), g1_7 = tanh_pre(b1.w);

    pa0 = *(const f4*)(wp + 200); pb0 = *(const f4*)(wp + 204);
    pc0 = *(const f4*)(wp + 208); pd0 = *(const f4*)(wp + 212);
    pa1 = pa0; pb1 = pb0; pc1 = pc0; pd1 = pd0;
#define L3STEP(GI, X0, X1) { \
    const float* wr = wp + 72 + (GI) * 16; \
    f4 w0 = *(const f4*)(wr); \
    f4 w1 = *(const f4*)(wr + 4); \
    f4 w2 = *(const f4*)(wr + 8); \
    f4 w3 = *(const f4*)(wr + 12); \
    f4 v0 = splat4(X0), v1 = splat4(X1); \
    pa0 += v0 * w0; pa1 += v1 * w0; \
    pb0 += v0 * w1; pb1 += v1 * w1; \
    pc0 += v0 * w2; pc1 += v1 * w2; \
    pd0 += v0 * w3; pd1 += v1 * w3; }
    L3STEP(0, g0_0, g1_0)
    L3STEP(1, g0_1, g1_1)
    L3STEP(2, g0_2, g1_2)
    L3STEP(3, g0_3, g1_3)
    L3STEP(4, g0_4, g1_4)
    L3STEP(5, g0_5, g1_5)
    L3STEP(6, g0_6, g1_6)
    L3STEP(7, g0_7, g1_7)
#undef L3STEP
}

// ---------------- fully fused single kernel ----------------------------------
// grid (256, 8): x = 128-sample tile, y = 8-dim group (y==7 slot7 -> dim 0).
// causality: y<4 -> l<32 -> only k<32 contributes (W1 pre-masked) -> 1 MFMA.
// Phase 2 now runs all 4 (dim, sample) chains through the spline as f4
// chain-major vectors: 4-way ILP through the serial exp/cumsum/select/log
// chain (was 2-way x 2 sequential calls) -> targets the 44% VALUBusy stall.
__global__ __launch_bounds__(256, 4) void fused_kernel(
    const float* __restrict__ x, const float* __restrict__ init_param,
    const float* __restrict__ W1, const float* __restrict__ b1,
    const float* __restrict__ W2, const float* __restrict__ b2,
    const float* __restrict__ W3, const float* __restrict__ b3,
    float* __restrict__ out)
{
    __shared__ ushort h1c[128 * H1S];    // 18432 B
    __shared__ float  wl[8 * WSL];       // 6912 B
    __shared__ ushort Blds[64 * BS];     // 9216 B  -> total 34560 B, 4 blocks/CU
    const int tid = threadIdx.x;
    const int s0 = blockIdx.x * 128;
    const int y  = blockIdx.y;
    const int bx = blockIdx.x;
    const int lane = tid & 63;
    const int wave = __builtin_amdgcn_readfirstlane(tid >> 6);
    const int ln = lane & 15, qg = lane >> 4;
    const int l0 = y * 8;

    // spline x values for this wave's 2 dims x 2 sample-halves
    const int dA = y * 8 + 1 + 2 * wave;
    const int dB = (y == 7 && wave == 3) ? 0 : dA + 1;
    const float* xr0 = x + (size_t)(s0 + lane) * 64;
    const float* xr1 = xr0 + 64 * 64;
    float xA0 = xr0[dA], xA1 = xr1[dA];
    float xB0 = xr0[dB], xB1 = xr1[dB];

    // A-fragments for two m-tiles (rows wave*16 and 64+wave*16)
    short8 a0_0, a1_0, a0_1, a1_1;
    {
        const float* p0 = x + (size_t)(s0 + wave * 16 + ln) * 64 + qg * 8;
        const float* p1 = p0 + 64 * 64;
        a0_0 = pack_a(*(const f4*)p0, *(const f4*)(p0 + 4));
        a0_1 = pack_a(*(const f4*)p1, *(const f4*)(p1 + 4));
        if (y >= 4) {
            a1_0 = pack_a(*(const f4*)(p0 + 32), *(const f4*)(p0 + 36));
            a1_1 = pack_a(*(const f4*)(p1 + 32), *(const f4*)(p1 + 36));
        } else { a1_0 = a0_0; a1_1 = a0_1; }
    }

    // ---- stage B-tile from W1: Blds[n_local][k] bf16, n = y*64+n_local ----
    // B[n][k] = W1[(l*63+k)*8+h], l=n>>3, h=n&7; 0 if n>=504 or k>=63.
    // y<4: only k<32 is ever read (causal) -> stage half.
    {
        const int n_local = tid >> 2;
        const int n = y * 64 + n_local;
        const int l = n >> 3, h = n & 7;
        const float* src = W1 + (size_t)l * 63 * 8 + h;   // + k*8 per k
        unsigned* drow = (unsigned*)&Blds[n_local * BS];
        if (y < 4) {
            const int kc0 = (tid & 3) * 8;
            #pragma unroll
            for (int j = 0; j < 4; ++j) {
                int k = kc0 + 2 * j;                      // k<32<63, n<256<504: no guards
                float v0 = src[(size_t)k * 8];
                float v1 = src[(size_t)(k + 1) * 8];
                drow[(kc0 >> 1) + j] = pack_bf16t2(v0, v1);
            }
        } else {
            const int kc0 = (tid & 3) * 16;
            #pragma unroll
            for (int j = 0; j < 8; ++j) {
                int k = kc0 + 2 * j;
                float v0 = (n < 504 && k < 63)     ? src[(size_t)k * 8]       : 0.f;
                float v1 = (n < 504 && k + 1 < 63) ? src[(size_t)(k + 1) * 8] : 0.f;
                drow[(kc0 >> 1) + j] = pack_bf16t2(v0, v1);
            }
        }
    }

    // ---- stage this block's 8 dims of weights into LDS (log2-domain scaled) ----
    if (tid < 128) {   // W2: 8 slots x 64 floats, f4, x 2log2e
        int s = tid >> 4, o = (tid & 15) * 4;
        if (l0 + s < LL)
            *(f4*)&wl[s * WSL + o] = splat4(TWOLOG2E) * (*(const f4*)&W2[(l0 + s) * 64 + o]);
    }
    if (tid < 64) {    // b2: 8 x 8, x 2log2e
        int s = tid >> 3, o = tid & 7;
        if (l0 + s < LL) wl[s * WSL + 64 + o] = TWOLOG2E * b2[(l0 + s) * 8 + o];
    }
    #pragma unroll
    for (int q0 = 0; q0 < 448; q0 += 256) {   // W3: 8 slots x 56 f2, x log2e
        int q = q0 + tid;
        if (q < 448) {
            int s = q / 56, r = q % 56, g = r / 7, o = r % 7;
            if (l0 + s < LL)
                *(f2*)&wl[s * WSL + 72 + g * 16 + o * 2] =
                    splat2(LOG2E) * (*(const f2*)&W3[(l0 + s) * 112 + g * 14 + o * 2]);
        }
    }
    if (tid < 64) {    // zero W3 pad cols 14,15
        int s = tid >> 3, g = tid & 7;
        *(f2*)&wl[s * WSL + 72 + g * 16 + 14] = splat2(0.f);
    }
    if (tid < 112) {   // b3: 8 x 14, x log2e
        int s = tid / 14, o = tid % 14;
        wl[s * WSL + 200 + o] = LOG2E * b3[(l0 + s < LL ? l0 + s : 0) * PP + o];
    }
    if (tid < 16) {    // zero b3 pad
        int s = tid >> 1, o = 214 + (tid & 1);
        wl[s * WSL + o] = 0.f;
    }
    __syncthreads();   // Blds + wl ready

    // ---- phase 1: MFMA 64 outcols x two 16-row m-tiles (B from LDS) ----
    #pragma unroll
    for (int nt = 0; nt < 4; ++nt) {
        int ncol = y * 64 + nt * 16 + ln;
        const ushort* brow = &Blds[(nt * 16 + ln) * BS + qg * 8];
        short8 bf0 = *(const short8*)brow;
        f32x4 acc0 = {0.f, 0.f, 0.f, 0.f};
        f32x4 acc1 = {0.f, 0.f, 0.f, 0.f};
        acc0 = __builtin_amdgcn_mfma_f32_16x16x32_bf16(a0_0, bf0, acc0, 0, 0, 0);
        acc1 = __builtin_amdgcn_mfma_f32_16x16x32_bf16(a0_1, bf0, acc1, 0, 0, 0);
        if (y >= 4) {
            short8 bf1 = *(const short8*)(brow + 32);
            acc0 = __builtin_amdgcn_mfma_f32_16x16x32_bf16(a1_0, bf1, acc0, 0, 0, 0);
            acc1 = __builtin_amdgcn_mfma_f32_16x16x32_bf16(a1_1, bf1, acc1, 0, 0, 0);
        }
        float bias2 = (ncol < 504) ? TWOLOG2E * b1[ncol] : 0.f;
        #pragma unroll
        for (int r = 0; r < 4; ++r) {
            int row = wave * 16 + qg * 4 + r;
            float v0 = tanh_pre(fmaf(TWOLOG2E, acc0[r], bias2));
            float v1 = tanh_pre(fmaf(TWOLOG2E, acc1[r], bias2));
            h1c[row * H1S + nt * 16 + ln] = to_bf16t(v0);
            h1c[(row + 64) * H1S + nt * 16 + ln] = to_bf16t(v1);
        }
    }
    __syncthreads();   // h1c ready

    // h1 fragments: 2 dims x 2 sample-halves
    const int slA = 2 * wave, slB = 2 * wave + 1;
    uint4 hA0 = *(const uint4*)&h1c[lane * H1S + slA * 8];
    uint4 hA1 = *(const uint4*)&h1c[(lane + 64) * H1S + slA * 8];
    uint4 hB0 = *(const uint4*)&h1c[lane * H1S + slB * 8];
    uint4 hB1 = *(const uint4*)&h1c[(lane + 64) * H1S + slB * 8];

    // ---- phase 2a: MLPs for both dims (sequential; ample internal ILP) ----
    f4 Aa0, Ab0, Ac0, Ad0, Aa1, Ab1, Ac1, Ad1;
    mlp2(wl + slA * WSL, hA0, hA1, Aa0, Ab0, Ac0, Ad0, Aa1, Ab1, Ac1, Ad1);
    f4 Ba0, Bb0, Bc0, Bd0, Ba1, Bb1, Bc1, Bd1;
    mlp2(wl + slB * WSL, hB0, hB1, Ba0, Bb0, Bc0, Bd0, Ba1, Bb1, Bc1, Bd1);

    if (dB == 0) {   // wave-uniform override (y==7, wave==3); log2 domain
        Ba0.x = LOG2E * init_param[0];  Ba0.y = LOG2E * init_param[1];
        Ba0.z = LOG2E * init_param[2];  Ba0.w = LOG2E * init_param[3];
        Bb0.x = LOG2E * init_param[4];  Bb0.y = LOG2E * init_param[5];
        Bb0.z = LOG2E * init_param[6];  Bb0.w = LOG2E * init_param[7];
        Bc0.x = LOG2E * init_param[8];  Bc0.y = LOG2E * init_param[9];
        Bc0.z = LOG2E * init_param[10]; Bc0.w = LOG2E * init_param[11];
        Bd0.x = LOG2E * init_param[12]; Bd0.y = LOG2E * init_param[13];
        Bd0.z = 0.f; Bd0.w = 0.f;
        Ba1 = Ba0; Bb1 = Bb0; Bc1 = Bc0; Bd1 = Bd0;
    }

    // ---- phase 2b: 4-chain spline, chain-major f4 = (A,s0),(A,s1),(B,s0),(B,s1)
    // PACKQ is pure register renaming (ext_vector comps are separate SSA vals).
#define PACKQ(name, va0, va1, vb0, vb1, c) \
    f4 name; name.x = va0.c; name.y = va1.c; name.z = vb0.c; name.w = vb1.c;
    PACKQ(p0q, Aa0, Aa1, Ba0, Ba1, x)
    PACKQ(p1q, Aa0, Aa1, Ba0, Ba1, y)
    PACKQ(p2q, Aa0, Aa1, Ba0, Ba1, z)
    PACKQ(p3q, Aa0, Aa1, Ba0, Ba1, w)
    PACKQ(p4q, Ab0, Ab1, Bb0, Bb1, x)
    PACKQ(p5q, Ab0, Ab1, Bb0, Bb1, y)
    PACKQ(p6q, Ab0, Ab1, Bb0, Bb1, z)
    PACKQ(p7q, Ab0, Ab1, Bb0, Bb1, w)
    PACKQ(p8q, Ac0, Ac1, Bc0, Bc1, x)
    PACKQ(p9q, Ac0, Ac1, Bc0, Bc1, y)
    PACKQ(r10, Ac0, Ac1, Bc0, Bc1, z)
    PACKQ(r11, Ac0, Ac1, Bc0, Bc1, w)
    PACKQ(r12, Ad0, Ad1, Bd0, Bd1, x)
    PACKQ(r13, Ad0, Ad1, Bd0, Bd1, y)
#undef PACKQ

    // softmax numerators (raw v_exp), 4 chains wide
    f4 ew0 = exp2_q(p0q), ew1 = exp2_q(p1q), ew2 = exp2_q(p2q),
       ew3 = exp2_q(p3q), ew4 = exp2_q(p4q);
    f4 eh0 = exp2_q(p5q), eh1 = exp2_q(p6q), eh2 = exp2_q(p7q),
       eh3 = exp2_q(p8q), eh4 = exp2_q(p9q);
    f4 esw = (ew0 + ew1) + (ew2 + ew3) + ew4;
    f4 esh = (eh0 + eh1) + (eh2 + eh3) + eh4;
    f4 nw = splat4(0.995f) * rcp_q(esw);
    f4 nh = splat4(0.995f) * rcp_q(esh);

    f4 accw = splat4(0.f), acch = splat4(0.f);
    accw += splat4(MIN_Wc) + nw * ew0;  f4 cbw1 = splat4(2.f * Bc) * accw - splat4(Bc);
    acch += splat4(MIN_Hc) + nh * eh0;  f4 cbh1 = splat4(2.f * Bc) * acch - splat4(Bc);
    accw += splat4(MIN_Wc) + nw * ew1;  f4 cbw2 = splat4(2.f * Bc) * accw - splat4(Bc);
    acch += splat4(MIN_Hc) + nh * eh1;  f4 cbh2 = splat4(2.f * Bc) * acch - splat4(Bc);
    accw += splat4(MIN_Wc) + nw * ew2;  f4 cbw3 = splat4(2.f * Bc) * accw - splat4(Bc);
    acch += splat4(MIN_Hc) + nh * eh2;  f4 cbh3 = splat4(2.f * Bc) * acch - splat4(Bc);
    accw += splat4(MIN_Wc) + nw * ew3;  f4 cbw4 = splat4(2.f * Bc) * accw - splat4(Bc);
    acch += splat4(MIN_Hc) + nh * eh3;  f4 cbh4 = splat4(2.f * Bc) * acch - splat4(Bc);

    f4 xfq; xfq.x = xA0; xfq.y = xA1; xfq.z = xB0; xfq.w = xB1;
    f4 xcq;
    #pragma unroll
    for (int c = 0; c < 4; ++c) xcq[c] = fminf(fmaxf(xfq[c], -Bc), Bc);

    // bin select: LOWER/UPPER boundary tracking, 4 chains interleaved per stage
    f4 icw = splat4(-Bc), ich = splat4(-Bc);
    f4 hwq = cbw1, hhq = cbh1;
    f4 rv = r10, rvp = r10;
    bool vone[4]  = {true, true, true, true};
    bool vpone[4];
    #pragma unroll
    for (int c = 0; c < 4; ++c) {
        bool t = xcq[c] >= cbw1[c];
        icw[c] = t ? cbw1[c] : icw[c];
        ich[c] = t ? cbh1[c] : ich[c];
        hwq[c] = t ? cbw2[c] : hwq[c];
        hhq[c] = t ? cbh2[c] : hhq[c];
        vone[c] = t ? false : vone[c];
        rvp[c] = t ? r11[c] : rvp[c];
    }
    #pragma unroll
    for (int c = 0; c < 4; ++c) {
        bool t = xcq[c] >= cbw2[c];
        icw[c] = t ? cbw2[c] : icw[c];
        ich[c] = t ? cbh2[c] : ich[c];
        hwq[c] = t ? cbw3[c] : hwq[c];
        hhq[c] = t ? cbh3[c] : hhq[c];
        rv[c]  = t ? r11[c] : rv[c];
        rvp[c] = t ? r12[c] : rvp[c];
    }
    #pragma unroll
    for (int c = 0; c < 4; ++c) {
        bool t = xcq[c] >= cbw3[c];
        icw[c] = t ? cbw3[c] : icw[c];
        ich[c] = t ? cbh3[c] : ich[c];
        hwq[c] = t ? cbw4[c] : hwq[c];
        hhq[c] = t ? cbh4[c] : hhq[c];
        rv[c]  = t ? r12[c] : rv[c];
        rvp[c] = t ? r13[c] : rvp[c];
    }
    #pragma unroll
    for (int c = 0; c < 4; ++c) {
        bool t = xcq[c] >= cbw4[c];
        icw[c] = t ? cbw4[c] : icw[c];
        ich[c] = t ? cbh4[c] : ich[c];
        hwq[c] = t ? Bc : hwq[c];
        hhq[c] = t ? Bc : hhq[c];
        rv[c]  = t ? r13[c] : rv[c];
        vpone[c] = t;
    }

    f4 ibw = hwq - icw, ihq = hhq - ich;
    f4 idv, idvp;
    #pragma unroll
    for (int c = 0; c < 4; ++c) {
        idv[c]  = vone[c]  ? 1.0f : MIN_Dc + softplus2(rv[c]);
        idvp[c] = vpone[c] ? 1.0f : MIN_Dc + softplus2(rvp[c]);
    }
    f4 ibr = rcp_q(ibw);
    f4 idl = ihq * ibr;
    f4 th  = (xcq - icw) * ibr;
    f4 om  = splat4(1.0f) - th;
    f4 tm  = th * om;
    f4 num = ihq * (idl * th * th + idv * tm);
    f4 den = idl + (idv + idvp - splat4(2.0f) * idl) * tm;
    f4 dr  = rcp_q(den);
    f4 outq = ich + num * dr;
    f4 dn  = idl * idl * (idvp * th * th + splat4(2.0f) * idl * tm + idv * om * om);
    f4 ldq;
    #pragma unroll
    for (int c = 0; c < 4; ++c) ldq[c] = LN2 * log2_fast(dn[c] * dr[c] * dr[c]);

    const bool in0 = (xA0 >= -Bc) && (xA0 <= Bc);
    const bool in1 = (xA1 >= -Bc) && (xA1 <= Bc);
    const bool in2 = (xB0 >= -Bc) && (xB0 <= Bc);
    const bool in3 = (xB1 >= -Bc) && (xB1 <= Bc);
    const float z0 = in0 ? outq.x : xA0;  float l0v = in0 ? ldq.x : 0.0f;
    const float z1 = in1 ? outq.y : xA1;  float l1v = in1 ? ldq.y : 0.0f;
    const float z2 = in2 ? outq.z : xB0;  float l2v = in2 ? ldq.z : 0.0f;
    const float z3 = in3 ? outq.w : xB1;  float l3v = in3 ? ldq.w : 0.0f;

    out[dA * NN + s0 + lane]      = z0;   // coalesced
    out[dA * NN + s0 + 64 + lane] = z1;
    out[dB * NN + s0 + lane]      = z2;
    out[dB * NN + s0 + 64 + lane] = z3;

    #pragma unroll
    for (int off = 32; off > 0; off >>= 1) {
        l0v += __shfl_down(l0v, off);
        l1v += __shfl_down(l1v, off);
        l2v += __shfl_down(l2v, off);
        l3v += __shfl_down(l3v, off);
    }
    if (lane == 0) {
        float* lo = out + NN * DD;
        lo[dA * (NN / 64) + 2 * bx]     = l0v;
        lo[dA * (NN / 64) + 2 * bx + 1] = l1v;
        lo[dB * (NN / 64) + 2 * bx]     = l2v;
        lo[dB * (NN / 64) + 2 * bx + 1] = l3v;
    }
}

extern "C" void kernel_launch(void* const* d_in, const int* in_sizes, int n_in,
                              void* d_out, int out_size, void* d_ws, size_t ws_size,
                              hipStream_t stream) {
    const float* x          = (const float*)d_in[0];
    const float* init_param = (const float*)d_in[1];
    const float* W1         = (const float*)d_in[2];
    const float* b1         = (const float*)d_in[3];
    const float* W2         = (const float*)d_in[4];
    const float* b2         = (const float*)d_in[5];
    const float* W3         = (const float*)d_in[6];
    const float* b3         = (const float*)d_in[7];
    float* out = (float*)d_out;

    // single launch; d_ws unused
    fused_kernel<<<dim3(256, 8), 256, 0, stream>>>(x, init_param, W1, b1,
                                                   W2, b2, W3, b3, out);
}

// Round 2
// 402.690 us; speedup vs baseline: 1.0143x; 1.0143x over previous
//
#include <hip/hip_runtime.h>
#include <hip/hip_bf16.h>
#include <math.h>

#define KK 5
#define Bc 5.0f
#define NN 32768
#define DD 64
#define LL 63
#define PP 14
#define MIN_Wc 0.001f
#define MIN_Hc 0.001f
#define MIN_Dc 0.001f
#define LOG2E 1.44269504088896340736f
#define TWOLOG2E 2.88539008177792681472f
#define LN2 0.69314718055994530942f

typedef float f4 __attribute__((ext_vector_type(4)));
typedef float f32x4 __attribute__((ext_vector_type(4)));
typedef float f2 __attribute__((ext_vector_type(2)));
typedef short short8 __attribute__((ext_vector_type(8)));

__device__ __forceinline__ float rcp_fast(float v)   { return __builtin_amdgcn_rcpf(v); }
__device__ __forceinline__ float exp2_fast(float v)  { return __builtin_amdgcn_exp2f(v); }  // v_exp_f32: 2^x
__device__ __forceinline__ float log2_fast(float v)  { return __builtin_amdgcn_logf(v); }   // v_log_f32: log2
// input pre-scaled by 2*log2(e): tanh(x) = 1 - 2/(2^(2x*log2e)+1)
__device__ __forceinline__ float tanh_pre(float t2) {
    float e = exp2_fast(t2);
    return 1.0f - 2.0f * rcp_fast(e + 1.0f);
}
// input pre-scaled by log2(e): softplus(v) = ln2*log2(1+2^(v*log2e))
__device__ __forceinline__ float softplus2(float v2) {
    return (v2 > 21.7f) ? LN2 * v2 : LN2 * log2_fast(1.0f + exp2_fast(v2));
}
// truncating bf16 (1 shift); absmax margin ~3x covers the extra ulp
__device__ __forceinline__ ushort to_bf16t(float v) {
    return (ushort)(__float_as_uint(v) >> 16);
}
// pack two fp32 -> one u32 of two truncated bf16 (lo=v0, hi=v1)
__device__ __forceinline__ unsigned pack_bf16t2(float v0, float v1) {
    return (__float_as_uint(v0) >> 16) | (__float_as_uint(v1) & 0xFFFF0000u);
}
__device__ __forceinline__ float bflo(unsigned u) { return __uint_as_float(u << 16); }
__device__ __forceinline__ float bfhi(unsigned u) { return __uint_as_float(u & 0xFFFF0000u); }
__device__ __forceinline__ f2 splat2(float v) { f2 r; r.x = v; r.y = v; return r; }
__device__ __forceinline__ f4 splat4(float v) { f4 r; r.x = v; r.y = v; r.z = v; r.w = v; return r; }
__device__ __forceinline__ f4 exp2_q(f4 v) {
    f4 r; r.x = exp2_fast(v.x); r.y = exp2_fast(v.y); r.z = exp2_fast(v.z); r.w = exp2_fast(v.w); return r;
}
__device__ __forceinline__ f4 rcp_q(f4 v) {
    f4 r; r.x = rcp_fast(v.x); r.y = rcp_fast(v.y); r.z = rcp_fast(v.z); r.w = rcp_fast(v.w); return r;
}

__device__ __forceinline__ short8 pack_a(f4 v0, f4 v1) {
    short8 a;
    a[0] = (short)to_bf16t(v0.x); a[1] = (short)to_bf16t(v0.y);
    a[2] = (short)to_bf16t(v0.z); a[3] = (short)to_bf16t(v0.w);
    a[4] = (short)to_bf16t(v1.x); a[5] = (short)to_bf16t(v1.y);
    a[6] = (short)to_bf16t(v1.z); a[7] = (short)to_bf16t(v1.w);
    return a;
}

// per-dim LDS weight slot (floats, stride 216 = 864B, 16B-aligned):
// [0,64) 2log2e*W2[h][g]  [64,72) 2log2e*b2  [72,200) log2e*W3 padded [g][16]  [200,216) log2e*b3
#define WSL 216
#define H1S 72    // u16 row stride: 144B (proven residue, 0 measured conflicts)
#define BS  72    // Blds u16 row stride (same proven residue)

// ---- L2+L3 MLP for one dim, TWO samples; p out in log2 domain --------------
// (weights pre-scaled: W2/b2 by 2log2e, W3/b3 by log2e at staging time)
__device__ __forceinline__ void mlp2(
    const float* wp, uint4 hv0, uint4 hv1,
    f4& pa0, f4& pb0, f4& pc0, f4& pd0,
    f4& pa1, f4& pb1, f4& pc1, f4& pd1)
{
    float h0_0 = bflo(hv0.x), h1_0 = bflo(hv1.x);
    float h0_1 = bfhi(hv0.x), h1_1 = bfhi(hv1.x);
    float h0_2 = bflo(hv0.y), h1_2 = bflo(hv1.y);
    float h0_3 = bfhi(hv0.y), h1_3 = bfhi(hv1.y);
    float h0_4 = bflo(hv0.z), h1_4 = bflo(hv1.z);
    float h0_5 = bfhi(hv0.z), h1_5 = bfhi(hv1.z);
    float h0_6 = bflo(hv0.w), h1_6 = bflo(hv1.w);
    float h0_7 = bfhi(hv0.w), h1_7 = bfhi(hv1.w);

    f4 a0 = *(const f4*)(wp + 64), b0 = *(const f4*)(wp + 68);
    f4 a1 = a0, b1 = b0;
#define L2STEP(HI, X0, X1) { \
    f4 wa = *(const f4*)(wp + (HI) * 8); \
    f4 wb = *(const f4*)(wp + (HI) * 8 + 4); \
    f4 v0 = splat4(X0), v1 = splat4(X1); \
    a0 += v0 * wa; a1 += v1 * wa; \
    b0 += v0 * wb; b1 += v1 * wb; }
    L2STEP(0, h0_0, h1_0)
    L2STEP(1, h0_1, h1_1)
    L2STEP(2, h0_2, h1_2)
    L2STEP(3, h0_3, h1_3)
    L2STEP(4, h0_4, h1_4)
    L2STEP(5, h0_5, h1_5)
    L2STEP(6, h0_6, h1_6)
    L2STEP(7, h0_7, h1_7)
#undef L2STEP
    float g0_0 = tanh_pre(a0.x), g1_0 = tanh_pre(a1.x);
    float g0_1 = tanh_pre(a0.y), g1_1 = tanh_pre(a1.y);
    float g0_2 = tanh_pre(a0.z), g1_2 = tanh_pre(a1.z);
    float g0_3 = tanh_pre(a0.w), g1_3 = tanh_pre(a1.w);
    float g0_4 = tanh_pre(b0.x), g1_4 = tanh_pre(b1.x);
    float g0_5 = tanh_pre(b0.y), g1_5 = tanh_pre(b1.y);
    float g0_6 = tanh_pre(b0.z), g1_6 = tanh_pre(b1.z);
    float g0_7 = tanh_pre(b0.w), g1_7 = tanh_pre(b1.w);

    pa0 = *(const f4*)(wp + 200); pb0 = *(const f4*)(wp + 204);
    pc0 = *(const f4*)(wp + 208); pd0 = *(const f4*)(wp + 212);
    pa1 = pa0; pb1 = pb0; pc1 = pc0; pd1 = pd0;
#define L3STEP(GI, X0, X1) { \
    const float* wr = wp + 72 + (GI) * 16; \
    f4 w0 = *(const f4*)(wr); \
    f4 w1 = *(const f4*)(wr + 4); \
    f4 w2 = *(const f4*)(wr + 8); \
    f4 w3 = *(const f4*)(wr + 12); \
    f4 v0 = splat4(X0), v1 = splat4(X1); \
    pa0 += v0 * w0; pa1 += v1 * w0; \
    pb0 += v0 * w1; pb1 += v1 * w1; \
    pc0 += v0 * w2; pc1 += v1 * w2; \
    pd0 += v0 * w3; pd1 += v1 * w3; }
    L3STEP(0, g0_0, g1_0)
    L3STEP(1, g0_1, g1_1)
    L3STEP(2, g0_2, g1_2)
    L3STEP(3, g0_3, g1_3)
    L3STEP(4, g0_4, g1_4)
    L3STEP(5, g0_5, g1_5)
    L3STEP(6, g0_6, g1_6)
    L3STEP(7, g0_7, g1_7)
#undef L3STEP
}

// ---------------- fully fused single kernel ----------------------------------
// grid (256, 8): x = 128-sample tile, y = 8-dim group (y==7 slot7 -> dim 0).
// causality: y<4 -> l<32 -> only k<32 contributes (W1 pre-masked) -> 1 MFMA.
// Phase 2b runs all 4 (dim, sample) chains through the spline chain-major.
// RULE #20: every ext_vector element access below is a compile-time
// component (.x/.y/.z/.w) — dynamic subscripts (even pragma-unrolled)
// lower to scratch allocas (R1: 1.1 GB scratch traffic, 9.5x slowdown).
__global__ __launch_bounds__(256, 4) void fused_kernel(
    const float* __restrict__ x, const float* __restrict__ init_param,
    const float* __restrict__ W1, const float* __restrict__ b1,
    const float* __restrict__ W2, const float* __restrict__ b2,
    const float* __restrict__ W3, const float* __restrict__ b3,
    float* __restrict__ out)
{
    __shared__ ushort h1c[128 * H1S];    // 18432 B
    __shared__ float  wl[8 * WSL];       // 6912 B
    __shared__ ushort Blds[64 * BS];     // 9216 B  -> total 34560 B, 4 blocks/CU
    const int tid = threadIdx.x;
    const int s0 = blockIdx.x * 128;
    const int y  = blockIdx.y;
    const int bx = blockIdx.x;
    const int lane = tid & 63;
    const int wave = __builtin_amdgcn_readfirstlane(tid >> 6);
    const int ln = lane & 15, qg = lane >> 4;
    const int l0 = y * 8;

    // spline x values for this wave's 2 dims x 2 sample-halves
    const int dA = y * 8 + 1 + 2 * wave;
    const int dB = (y == 7 && wave == 3) ? 0 : dA + 1;
    const float* xr0 = x + (size_t)(s0 + lane) * 64;
    const float* xr1 = xr0 + 64 * 64;
    float xA0 = xr0[dA], xA1 = xr1[dA];
    float xB0 = xr0[dB], xB1 = xr1[dB];

    // A-fragments for two m-tiles (rows wave*16 and 64+wave*16)
    short8 a0_0, a1_0, a0_1, a1_1;
    {
        const float* p0 = x + (size_t)(s0 + wave * 16 + ln) * 64 + qg * 8;
        const float* p1 = p0 + 64 * 64;
        a0_0 = pack_a(*(const f4*)p0, *(const f4*)(p0 + 4));
        a0_1 = pack_a(*(const f4*)p1, *(const f4*)(p1 + 4));
        if (y >= 4) {
            a1_0 = pack_a(*(const f4*)(p0 + 32), *(const f4*)(p0 + 36));
            a1_1 = pack_a(*(const f4*)(p1 + 32), *(const f4*)(p1 + 36));
        } else { a1_0 = a0_0; a1_1 = a0_1; }
    }

    // ---- stage B-tile from W1: Blds[n_local][k] bf16, n = y*64+n_local ----
    // B[n][k] = W1[(l*63+k)*8+h], l=n>>3, h=n&7; 0 if n>=504 or k>=63.
    // y<4: only k<32 is ever read (causal) -> stage half.
    {
        const int n_local = tid >> 2;
        const int n = y * 64 + n_local;
        const int l = n >> 3, h = n & 7;
        const float* src = W1 + (size_t)l * 63 * 8 + h;   // + k*8 per k
        unsigned* drow = (unsigned*)&Blds[n_local * BS];
        if (y < 4) {
            const int kc0 = (tid & 3) * 8;
            #pragma unroll
            for (int j = 0; j < 4; ++j) {
                int k = kc0 + 2 * j;                      // k<32<63, n<256<504: no guards
                float v0 = src[(size_t)k * 8];
                float v1 = src[(size_t)(k + 1) * 8];
                drow[(kc0 >> 1) + j] = pack_bf16t2(v0, v1);
            }
        } else {
            const int kc0 = (tid & 3) * 16;
            #pragma unroll
            for (int j = 0; j < 8; ++j) {
                int k = kc0 + 2 * j;
                float v0 = (n < 504 && k < 63)     ? src[(size_t)k * 8]       : 0.f;
                float v1 = (n < 504 && k + 1 < 63) ? src[(size_t)(k + 1) * 8] : 0.f;
                drow[(kc0 >> 1) + j] = pack_bf16t2(v0, v1);
            }
        }
    }

    // ---- stage this block's 8 dims of weights into LDS (log2-domain scaled) ----
    if (tid < 128) {   // W2: 8 slots x 64 floats, f4, x 2log2e
        int s = tid >> 4, o = (tid & 15) * 4;
        if (l0 + s < LL)
            *(f4*)&wl[s * WSL + o] = splat4(TWOLOG2E) * (*(const f4*)&W2[(l0 + s) * 64 + o]);
    }
    if (tid < 64) {    // b2: 8 x 8, x 2log2e
        int s = tid >> 3, o = tid & 7;
        if (l0 + s < LL) wl[s * WSL + 64 + o] = TWOLOG2E * b2[(l0 + s) * 8 + o];
    }
    #pragma unroll
    for (int q0 = 0; q0 < 448; q0 += 256) {   // W3: 8 slots x 56 f2, x log2e
        int q = q0 + tid;
        if (q < 448) {
            int s = q / 56, r = q % 56, g = r / 7, o = r % 7;
            if (l0 + s < LL)
                *(f2*)&wl[s * WSL + 72 + g * 16 + o * 2] =
                    splat2(LOG2E) * (*(const f2*)&W3[(l0 + s) * 112 + g * 14 + o * 2]);
        }
    }
    if (tid < 64) {    // zero W3 pad cols 14,15
        int s = tid >> 3, g = tid & 7;
        *(f2*)&wl[s * WSL + 72 + g * 16 + 14] = splat2(0.f);
    }
    if (tid < 112) {   // b3: 8 x 14, x log2e
        int s = tid / 14, o = tid % 14;
        wl[s * WSL + 200 + o] = LOG2E * b3[(l0 + s < LL ? l0 + s : 0) * PP + o];
    }
    if (tid < 16) {    // zero b3 pad
        int s = tid >> 1, o = 214 + (tid & 1);
        wl[s * WSL + o] = 0.f;
    }
    __syncthreads();   // Blds + wl ready

    // ---- phase 1: MFMA 64 outcols x two 16-row m-tiles (B from LDS) ----
    #pragma unroll
    for (int nt = 0; nt < 4; ++nt) {
        int ncol = y * 64 + nt * 16 + ln;
        const ushort* brow = &Blds[(nt * 16 + ln) * BS + qg * 8];
        short8 bf0 = *(const short8*)brow;
        f32x4 acc0 = {0.f, 0.f, 0.f, 0.f};
        f32x4 acc1 = {0.f, 0.f, 0.f, 0.f};
        acc0 = __builtin_amdgcn_mfma_f32_16x16x32_bf16(a0_0, bf0, acc0, 0, 0, 0);
        acc1 = __builtin_amdgcn_mfma_f32_16x16x32_bf16(a0_1, bf0, acc1, 0, 0, 0);
        if (y >= 4) {
            short8 bf1 = *(const short8*)(brow + 32);
            acc0 = __builtin_amdgcn_mfma_f32_16x16x32_bf16(a1_0, bf1, acc0, 0, 0, 0);
            acc1 = __builtin_amdgcn_mfma_f32_16x16x32_bf16(a1_1, bf1, acc1, 0, 0, 0);
        }
        float bias2 = (ncol < 504) ? TWOLOG2E * b1[ncol] : 0.f;
        #pragma unroll
        for (int r = 0; r < 4; ++r) {
            int row = wave * 16 + qg * 4 + r;
            float v0 = tanh_pre(fmaf(TWOLOG2E, acc0[r], bias2));
            float v1 = tanh_pre(fmaf(TWOLOG2E, acc1[r], bias2));
            h1c[row * H1S + nt * 16 + ln] = to_bf16t(v0);
            h1c[(row + 64) * H1S + nt * 16 + ln] = to_bf16t(v1);
        }
    }
    __syncthreads();   // h1c ready

    // h1 fragments: 2 dims x 2 sample-halves
    const int slA = 2 * wave, slB = 2 * wave + 1;
    uint4 hA0 = *(const uint4*)&h1c[lane * H1S + slA * 8];
    uint4 hA1 = *(const uint4*)&h1c[(lane + 64) * H1S + slA * 8];
    uint4 hB0 = *(const uint4*)&h1c[lane * H1S + slB * 8];
    uint4 hB1 = *(const uint4*)&h1c[(lane + 64) * H1S + slB * 8];

    // ---- phase 2a: MLPs for both dims (sequential; ample internal ILP) ----
    f4 Aa0, Ab0, Ac0, Ad0, Aa1, Ab1, Ac1, Ad1;
    mlp2(wl + slA * WSL, hA0, hA1, Aa0, Ab0, Ac0, Ad0, Aa1, Ab1, Ac1, Ad1);
    f4 Ba0, Bb0, Bc0, Bd0, Ba1, Bb1, Bc1, Bd1;
    mlp2(wl + slB * WSL, hB0, hB1, Ba0, Bb0, Bc0, Bd0, Ba1, Bb1, Bc1, Bd1);

    if (dB == 0) {   // wave-uniform override (y==7, wave==3); log2 domain
        Ba0.x = LOG2E * init_param[0];  Ba0.y = LOG2E * init_param[1];
        Ba0.z = LOG2E * init_param[2];  Ba0.w = LOG2E * init_param[3];
        Bb0.x = LOG2E * init_param[4];  Bb0.y = LOG2E * init_param[5];
        Bb0.z = LOG2E * init_param[6];  Bb0.w = LOG2E * init_param[7];
        Bc0.x = LOG2E * init_param[8];  Bc0.y = LOG2E * init_param[9];
        Bc0.z = LOG2E * init_param[10]; Bc0.w = LOG2E * init_param[11];
        Bd0.x = LOG2E * init_param[12]; Bd0.y = LOG2E * init_param[13];
        Bd0.z = 0.f; Bd0.w = 0.f;
        Ba1 = Ba0; Bb1 = Bb0; Bc1 = Bc0; Bd1 = Bd0;
    }

    // ---- phase 2b: 4-chain spline, chain-major f4 = (A,s0),(A,s1),(B,s0),(B,s1)
    // PACKQ is pure register renaming (ext_vector comps are separate SSA vals).
#define PACKQ(name, va0, va1, vb0, vb1, c) \
    f4 name; name.x = va0.c; name.y = va1.c; name.z = vb0.c; name.w = vb1.c;
    PACKQ(p0q, Aa0, Aa1, Ba0, Ba1, x)
    PACKQ(p1q, Aa0, Aa1, Ba0, Ba1, y)
    PACKQ(p2q, Aa0, Aa1, Ba0, Ba1, z)
    PACKQ(p3q, Aa0, Aa1, Ba0, Ba1, w)
    PACKQ(p4q, Ab0, Ab1, Bb0, Bb1, x)
    PACKQ(p5q, Ab0, Ab1, Bb0, Bb1, y)
    PACKQ(p6q, Ab0, Ab1, Bb0, Bb1, z)
    PACKQ(p7q, Ab0, Ab1, Bb0, Bb1, w)
    PACKQ(p8q, Ac0, Ac1, Bc0, Bc1, x)
    PACKQ(p9q, Ac0, Ac1, Bc0, Bc1, y)
    PACKQ(r10, Ac0, Ac1, Bc0, Bc1, z)
    PACKQ(r11, Ac0, Ac1, Bc0, Bc1, w)
    PACKQ(r12, Ad0, Ad1, Bd0, Bd1, x)
    PACKQ(r13, Ad0, Ad1, Bd0, Bd1, y)
#undef PACKQ

    // softmax numerators (raw v_exp), 4 chains wide
    f4 ew0 = exp2_q(p0q), ew1 = exp2_q(p1q), ew2 = exp2_q(p2q),
       ew3 = exp2_q(p3q), ew4 = exp2_q(p4q);
    f4 eh0 = exp2_q(p5q), eh1 = exp2_q(p6q), eh2 = exp2_q(p7q),
       eh3 = exp2_q(p8q), eh4 = exp2_q(p9q);
    f4 esw = (ew0 + ew1) + (ew2 + ew3) + ew4;
    f4 esh = (eh0 + eh1) + (eh2 + eh3) + eh4;
    f4 nw = splat4(0.995f) * rcp_q(esw);
    f4 nh = splat4(0.995f) * rcp_q(esh);

    f4 accw = splat4(0.f), acch = splat4(0.f);
    accw += splat4(MIN_Wc) + nw * ew0;  f4 cbw1 = splat4(2.f * Bc) * accw - splat4(Bc);
    acch += splat4(MIN_Hc) + nh * eh0;  f4 cbh1 = splat4(2.f * Bc) * acch - splat4(Bc);
    accw += splat4(MIN_Wc) + nw * ew1;  f4 cbw2 = splat4(2.f * Bc) * accw - splat4(Bc);
    acch += splat4(MIN_Hc) + nh * eh1;  f4 cbh2 = splat4(2.f * Bc) * acch - splat4(Bc);
    accw += splat4(MIN_Wc) + nw * ew2;  f4 cbw3 = splat4(2.f * Bc) * accw - splat4(Bc);
    acch += splat4(MIN_Hc) + nh * eh2;  f4 cbh3 = splat4(2.f * Bc) * acch - splat4(Bc);
    accw += splat4(MIN_Wc) + nw * ew3;  f4 cbw4 = splat4(2.f * Bc) * accw - splat4(Bc);
    acch += splat4(MIN_Hc) + nh * eh3;  f4 cbh4 = splat4(2.f * Bc) * acch - splat4(Bc);

    f4 xcq;
    xcq.x = fminf(fmaxf(xA0, -Bc), Bc);
    xcq.y = fminf(fmaxf(xA1, -Bc), Bc);
    xcq.z = fminf(fmaxf(xB0, -Bc), Bc);
    xcq.w = fminf(fmaxf(xB1, -Bc), Bc);

    // bin select: LOWER/UPPER boundary tracking; per-chain macro, chains
    // mutually independent (scheduler interleaves the 4 expansions).
    f4 icw = splat4(-Bc), ich = splat4(-Bc);
    f4 hwq = cbw1, hhq = cbh1;
    f4 rv = r10, rvp = r10;
    bool vone0, vone1, vone2, vone3;
    bool vpone0, vpone1, vpone2, vpone3;
#define BSEL(C, VONE, VPONE) { \
    bool t1 = xcq.C >= cbw1.C; \
    icw.C = t1 ? cbw1.C : icw.C;  ich.C = t1 ? cbh1.C : ich.C; \
    hwq.C = t1 ? cbw2.C : hwq.C;  hhq.C = t1 ? cbh2.C : hhq.C; \
    VONE = !t1;                   rvp.C = t1 ? r11.C : rvp.C; \
    bool t2 = xcq.C >= cbw2.C; \
    icw.C = t2 ? cbw2.C : icw.C;  ich.C = t2 ? cbh2.C : ich.C; \
    hwq.C = t2 ? cbw3.C : hwq.C;  hhq.C = t2 ? cbh3.C : hhq.C; \
    rv.C  = t2 ? r11.C : rv.C;    rvp.C = t2 ? r12.C : rvp.C; \
    bool t3 = xcq.C >= cbw3.C; \
    icw.C = t3 ? cbw3.C : icw.C;  ich.C = t3 ? cbh3.C : ich.C; \
    hwq.C = t3 ? cbw4.C : hwq.C;  hhq.C = t3 ? cbh4.C : hhq.C; \
    rv.C  = t3 ? r12.C : rv.C;    rvp.C = t3 ? r13.C : rvp.C; \
    bool t4 = xcq.C >= cbw4.C; \
    icw.C = t4 ? cbw4.C : icw.C;  ich.C = t4 ? cbh4.C : ich.C; \
    hwq.C = t4 ? Bc : hwq.C;      hhq.C = t4 ? Bc : hhq.C; \
    rv.C  = t4 ? r13.C : rv.C;    VPONE = t4; }
    BSEL(x, vone0, vpone0)
    BSEL(y, vone1, vpone1)
    BSEL(z, vone2, vpone2)
    BSEL(w, vone3, vpone3)
#undef BSEL

    f4 ibw = hwq - icw, ihq = hhq - ich;
    f4 idv, idvp;
    idv.x  = vone0  ? 1.0f : MIN_Dc + softplus2(rv.x);
    idv.y  = vone1  ? 1.0f : MIN_Dc + softplus2(rv.y);
    idv.z  = vone2  ? 1.0f : MIN_Dc + softplus2(rv.z);
    idv.w  = vone3  ? 1.0f : MIN_Dc + softplus2(rv.w);
    idvp.x = vpone0 ? 1.0f : MIN_Dc + softplus2(rvp.x);
    idvp.y = vpone1 ? 1.0f : MIN_Dc + softplus2(rvp.y);
    idvp.z = vpone2 ? 1.0f : MIN_Dc + softplus2(rvp.z);
    idvp.w = vpone3 ? 1.0f : MIN_Dc + softplus2(rvp.w);

    f4 ibr = rcp_q(ibw);
    f4 idl = ihq * ibr;
    f4 th  = (xcq - icw) * ibr;
    f4 om  = splat4(1.0f) - th;
    f4 tm  = th * om;
    f4 num = ihq * (idl * th * th + idv * tm);
    f4 den = idl + (idv + idvp - splat4(2.0f) * idl) * tm;
    f4 dr  = rcp_q(den);
    f4 outq = ich + num * dr;
    f4 dn  = idl * idl * (idvp * th * th + splat4(2.0f) * idl * tm + idv * om * om);
    f4 ldq;
    ldq.x = LN2 * log2_fast(dn.x * dr.x * dr.x);
    ldq.y = LN2 * log2_fast(dn.y * dr.y * dr.y);
    ldq.z = LN2 * log2_fast(dn.z * dr.z * dr.z);
    ldq.w = LN2 * log2_fast(dn.w * dr.w * dr.w);

    const bool in0 = (xA0 >= -Bc) && (xA0 <= Bc);
    const bool in1 = (xA1 >= -Bc) && (xA1 <= Bc);
    const bool in2 = (xB0 >= -Bc) && (xB0 <= Bc);
    const bool in3 = (xB1 >= -Bc) && (xB1 <= Bc);
    const float z0 = in0 ? outq.x : xA0;  float l0v = in0 ? ldq.x : 0.0f;
    const float z1 = in1 ? outq.y : xA1;  float l1v = in1 ? ldq.y : 0.0f;
    const float z2 = in2 ? outq.z : xB0;  float l2v = in2 ? ldq.z : 0.0f;
    const float z3 = in3 ? outq.w : xB1;  float l3v = in3 ? ldq.w : 0.0f;

    out[dA * NN + s0 + lane]      = z0;   // coalesced
    out[dA * NN + s0 + 64 + lane] = z1;
    out[dB * NN + s0 + lane]      = z2;
    out[dB * NN + s0 + 64 + lane] = z3;

    #pragma unroll
    for (int off = 32; off > 0; off >>= 1) {
        l0v += __shfl_down(l0v, off);
        l1v += __shfl_down(l1v, off);
        l2v += __shfl_down(l2v, off);
        l3v += __shfl_down(l3v, off);
    }
    if (lane == 0) {
        float* lo = out + NN * DD;
        lo[dA * (NN / 64) + 2 * bx]     = l0v;
        lo[dA * (NN / 64) + 2 * bx + 1] = l1v;
        lo[dB * (NN / 64) + 2 * bx]     = l2v;
        lo[dB * (NN / 64) + 2 * bx + 1] = l3v;
    }
}

extern "C" void kernel_launch(void* const* d_in, const int* in_sizes, int n_in,
                              void* d_out, int out_size, void* d_ws, size_t ws_size,
                              hipStream_t stream) {
    const float* x          = (const float*)d_in[0];
    const float* init_param = (const float*)d_in[1];
    const float* W1         = (const float*)d_in[2];
    const float* b1         = (const float*)d_in[3];
    const float* W2         = (const float*)d_in[4];
    const float* b2         = (const float*)d_in[5];
    const float* W3         = (const float*)d_in[6];
    const float* b3         = (const float*)d_in[7];
    float* out = (float*)d_out;

    // single launch; d_ws unused
    fused_kernel<<<dim3(256, 8), 256, 0, stream>>>(x, init_param, W1, b1,
                                                   W2, b2, W3, b3, out);
}

// Round 4
// 225.758 us; speedup vs baseline: 1.8093x; 1.7837x over previous
//
#include <hip/hip_runtime.h>
#include <hip/hip_bf16.h>
#include <math.h>

#define KK 5
#define Bc 5.0f
#define NN 32768
#define DD 64
#define LL 63
#define PP 14
#define MIN_Wc 0.001f
#define MIN_Hc 0.001f
#define MIN_Dc 0.001f
#define LOG2E 1.44269504088896340736f
#define TWOLOG2E 2.88539008177792681472f
#define LN2 0.69314718055994530942f

typedef float f4 __attribute__((ext_vector_type(4)));
typedef float f32x4 __attribute__((ext_vector_type(4)));
typedef float f2 __attribute__((ext_vector_type(2)));
typedef short short8 __attribute__((ext_vector_type(8)));

__device__ __forceinline__ float rcp_fast(float v)   { return __builtin_amdgcn_rcpf(v); }
__device__ __forceinline__ float exp2_fast(float v)  { return __builtin_amdgcn_exp2f(v); }
__device__ __forceinline__ float log2_fast(float v)  { return __builtin_amdgcn_logf(v); }
__device__ __forceinline__ float tanh_pre(float t2) {
    float e = exp2_fast(t2);
    return 1.0f - 2.0f * rcp_fast(e + 1.0f);
}
__device__ __forceinline__ float softplus2(float v2) {
    return (v2 > 21.7f) ? LN2 * v2 : LN2 * log2_fast(1.0f + exp2_fast(v2));
}
__device__ __forceinline__ ushort to_bf16t(float v) {
    return (ushort)(__float_as_uint(v) >> 16);
}
__device__ __forceinline__ unsigned pack_bf16t2(float v0, float v1) {
    return (__float_as_uint(v0) >> 16) | (__float_as_uint(v1) & 0xFFFF0000u);
}
__device__ __forceinline__ float bflo(unsigned u) { return __uint_as_float(u << 16); }
__device__ __forceinline__ float bfhi(unsigned u) { return __uint_as_float(u & 0xFFFF0000u); }
__device__ __forceinline__ f2 splat2(float v) { f2 r; r.x = v; r.y = v; return r; }
__device__ __forceinline__ f4 splat4(float v) { f4 r; r.x = v; r.y = v; r.z = v; r.w = v; return r; }

__device__ __forceinline__ short8 pack_a(f4 v0, f4 v1) {
    short8 a;
    a[0] = (short)to_bf16t(v0.x); a[1] = (short)to_bf16t(v0.y);
    a[2] = (short)to_bf16t(v0.z); a[3] = (short)to_bf16t(v0.w);
    a[4] = (short)to_bf16t(v1.x); a[5] = (short)to_bf16t(v1.y);
    a[6] = (short)to_bf16t(v1.z); a[7] = (short)to_bf16t(v1.w);
    return a;
}

// per-dim LDS weight slot (floats, stride 216 = 864B, 16B-aligned):
// [0,64) 2log2e*W2[h][g]  [64,72) 2log2e*b2  [72,200) log2e*W3 padded [g][16]  [200,216) log2e*b3
#define WSL 216
#define H1S 72    // u16 row stride: 144B (proven residue, 0 measured conflicts)
#define BS  72    // Blds u16 row stride (same proven residue)

// ============ macros: all state in NAMED SCALARS (R0-proven patterns only) ==
// R1/R2 lesson: the f4-heavy top-level rewrite put the whole spline working
// set in un-promoted allocas (1.1 GB scratch traffic, VGPR=64). This version
// is R0's measured-clean do_dim2 body textually widened to 4 chains.
// TOKEN-PASTE rule (R3 compile fail): digits lead the pasted name (e0##S),
// never trail into a .member (e##S##0.x lexes "0.x" as one pp-number).

#define MLP_L2(HI, X0, X1) { \
    f4 wa = *(const f4*)(wp_ + (HI) * 8); \
    f4 wb = *(const f4*)(wp_ + (HI) * 8 + 4); \
    f4 v0 = splat4(X0), v1 = splat4(X1); \
    a0 += v0 * wa; a1 += v1 * wa; \
    b0 += v0 * wb; b1 += v1 * wb; }

#define MLP_L3(GI, X0, X1) { \
    const float* wr = wp_ + 72 + (GI) * 16; \
    f4 w0 = *(const f4*)(wr); \
    f4 w1 = *(const f4*)(wr + 4); \
    f4 w2 = *(const f4*)(wr + 8); \
    f4 w3 = *(const f4*)(wr + 12); \
    f4 v0 = splat4(X0), v1 = splat4(X1); \
    pa0 += v0 * w0; pa1 += v1 * w0; \
    pb0 += v0 * w1; pb1 += v1 * w1; \
    pc0 += v0 * w2; pc1 += v1 * w2; \
    pd0 += v0 * w3; pd1 += v1 * w3; }

#define MLP_BLOCK(S, WP, HV0, HV1) { \
    const float* wp_ = (WP); \
    float h00 = bflo((HV0).x), h10 = bflo((HV1).x); \
    float h01 = bfhi((HV0).x), h11 = bfhi((HV1).x); \
    float h02 = bflo((HV0).y), h12 = bflo((HV1).y); \
    float h03 = bfhi((HV0).y), h13 = bfhi((HV1).y); \
    float h04 = bflo((HV0).z), h14 = bflo((HV1).z); \
    float h05 = bfhi((HV0).z), h15 = bfhi((HV1).z); \
    float h06 = bflo((HV0).w), h16 = bflo((HV1).w); \
    float h07 = bfhi((HV0).w), h17 = bfhi((HV1).w); \
    f4 a0 = *(const f4*)(wp_ + 64), b0 = *(const f4*)(wp_ + 68); \
    f4 a1 = a0, b1 = b0; \
    MLP_L2(0, h00, h10) MLP_L2(1, h01, h11) \
    MLP_L2(2, h02, h12) MLP_L2(3, h03, h13) \
    MLP_L2(4, h04, h14) MLP_L2(5, h05, h15) \
    MLP_L2(6, h06, h16) MLP_L2(7, h07, h17) \
    float g00 = tanh_pre(a0.x), g10 = tanh_pre(a1.x); \
    float g01 = tanh_pre(a0.y), g11 = tanh_pre(a1.y); \
    float g02 = tanh_pre(a0.z), g12 = tanh_pre(a1.z); \
    float g03 = tanh_pre(a0.w), g13 = tanh_pre(a1.w); \
    float g04 = tanh_pre(b0.x), g14 = tanh_pre(b1.x); \
    float g05 = tanh_pre(b0.y), g15 = tanh_pre(b1.y); \
    float g06 = tanh_pre(b0.z), g16 = tanh_pre(b1.z); \
    float g07 = tanh_pre(b0.w), g17 = tanh_pre(b1.w); \
    f4 pa0 = *(const f4*)(wp_ + 200), pb0 = *(const f4*)(wp_ + 204); \
    f4 pc0 = *(const f4*)(wp_ + 208), pd0 = *(const f4*)(wp_ + 212); \
    f4 pa1 = pa0, pb1 = pb0, pc1 = pc0, pd1 = pd0; \
    MLP_L3(0, g00, g10) MLP_L3(1, g01, g11) \
    MLP_L3(2, g02, g12) MLP_L3(3, g03, g13) \
    MLP_L3(4, g04, g14) MLP_L3(5, g05, g15) \
    MLP_L3(6, g06, g16) MLP_L3(7, g07, g17) \
    p##S##0_0 = pa0.x;  p##S##0_1 = pa0.y;  p##S##0_2 = pa0.z;  p##S##0_3 = pa0.w; \
    p##S##0_4 = pb0.x;  p##S##0_5 = pb0.y;  p##S##0_6 = pb0.z;  p##S##0_7 = pb0.w; \
    p##S##0_8 = pc0.x;  p##S##0_9 = pc0.y;  p##S##0_10 = pc0.z; p##S##0_11 = pc0.w; \
    p##S##0_12 = pd0.x; p##S##0_13 = pd0.y; \
    p##S##1_0 = pa1.x;  p##S##1_1 = pa1.y;  p##S##1_2 = pa1.z;  p##S##1_3 = pa1.w; \
    p##S##1_4 = pb1.x;  p##S##1_5 = pb1.y;  p##S##1_6 = pb1.z;  p##S##1_7 = pb1.w; \
    p##S##1_8 = pc1.x;  p##S##1_9 = pc1.y;  p##S##1_10 = pc1.z; p##S##1_11 = pc1.w; \
    p##S##1_12 = pd1.x; p##S##1_13 = pd1.y; }

#define EPACK(S) \
    f4 e0##S, e1##S, e2##S, e3##S, e4##S; \
    e0##S.x = exp2_fast(p##S##0_0); e0##S.y = exp2_fast(p##S##0_5); \
    e0##S.z = exp2_fast(p##S##1_0); e0##S.w = exp2_fast(p##S##1_5); \
    e1##S.x = exp2_fast(p##S##0_1); e1##S.y = exp2_fast(p##S##0_6); \
    e1##S.z = exp2_fast(p##S##1_1); e1##S.w = exp2_fast(p##S##1_6); \
    e2##S.x = exp2_fast(p##S##0_2); e2##S.y = exp2_fast(p##S##0_7); \
    e2##S.z = exp2_fast(p##S##1_2); e2##S.w = exp2_fast(p##S##1_7); \
    e3##S.x = exp2_fast(p##S##0_3); e3##S.y = exp2_fast(p##S##0_8); \
    e3##S.z = exp2_fast(p##S##1_3); e3##S.w = exp2_fast(p##S##1_8); \
    e4##S.x = exp2_fast(p##S##0_4); e4##S.y = exp2_fast(p##S##0_9); \
    e4##S.z = exp2_fast(p##S##1_4); e4##S.w = exp2_fast(p##S##1_9); \
    f4 es##S = (e0##S + e1##S) + (e2##S + e3##S) + e4##S; \
    f4 nrm##S; \
    nrm##S.x = 0.995f * rcp_fast(es##S.x); nrm##S.y = 0.995f * rcp_fast(es##S.y); \
    nrm##S.z = 0.995f * rcp_fast(es##S.z); nrm##S.w = 0.995f * rcp_fast(es##S.w); \
    f4 acc##S = splat4(0.f); \
    acc##S += minv + nrm##S * e0##S;  f4 cb1##S = splat4(2.f * Bc) * acc##S - splat4(Bc); \
    acc##S += minv + nrm##S * e1##S;  f4 cb2##S = splat4(2.f * Bc) * acc##S - splat4(Bc); \
    acc##S += minv + nrm##S * e2##S;  f4 cb3##S = splat4(2.f * Bc) * acc##S - splat4(Bc); \
    acc##S += minv + nrm##S * e3##S;  f4 cb4##S = splat4(2.f * Bc) * acc##S - splat4(Bc);

#define CASCADE(SUF, CBS, CW, CH, P10, P11, P12, P13, XC) \
    float icw##SUF = -Bc, ich##SUF = -Bc; \
    float hw##SUF = cb1##CBS.CW, hh##SUF = cb1##CBS.CH; \
    float rv##SUF = P10, rvp##SUF = P10; \
    bool vone##SUF = true, vpone##SUF = false; \
    { bool c = XC >= cb1##CBS.CW; \
      icw##SUF = c ? cb1##CBS.CW : icw##SUF;  ich##SUF = c ? cb1##CBS.CH : ich##SUF; \
      hw##SUF  = c ? cb2##CBS.CW : hw##SUF;   hh##SUF  = c ? cb2##CBS.CH : hh##SUF; \
      vone##SUF = !c;                         rvp##SUF = c ? P11 : rvp##SUF; } \
    { bool c = XC >= cb2##CBS.CW; \
      icw##SUF = c ? cb2##CBS.CW : icw##SUF;  ich##SUF = c ? cb2##CBS.CH : ich##SUF; \
      hw##SUF  = c ? cb3##CBS.CW : hw##SUF;   hh##SUF  = c ? cb3##CBS.CH : hh##SUF; \
      rv##SUF  = c ? P11 : rv##SUF;           rvp##SUF = c ? P12 : rvp##SUF; } \
    { bool c = XC >= cb3##CBS.CW; \
      icw##SUF = c ? cb3##CBS.CW : icw##SUF;  ich##SUF = c ? cb3##CBS.CH : ich##SUF; \
      hw##SUF  = c ? cb4##CBS.CW : hw##SUF;   hh##SUF  = c ? cb4##CBS.CH : hh##SUF; \
      rv##SUF  = c ? P12 : rv##SUF;           rvp##SUF = c ? P13 : rvp##SUF; } \
    { bool c = XC >= cb4##CBS.CW; \
      icw##SUF = c ? cb4##CBS.CW : icw##SUF;  ich##SUF = c ? cb4##CBS.CH : ich##SUF; \
      hw##SUF  = c ? Bc : hw##SUF;            hh##SUF  = c ? Bc : hh##SUF; \
      rv##SUF  = c ? P13 : rv##SUF;           vpone##SUF = c; }

#define CHAIN_FIN(SUF, XC, XF, ZV, LV) \
    const float ibw##SUF = hw##SUF - icw##SUF, ih##SUF = hh##SUF - ich##SUF; \
    const float idv##SUF  = vone##SUF  ? 1.0f : MIN_Dc + softplus2(rv##SUF); \
    const float idvp##SUF = vpone##SUF ? 1.0f : MIN_Dc + softplus2(rvp##SUF); \
    const float ibr##SUF = rcp_fast(ibw##SUF); \
    const float idl##SUF = ih##SUF * ibr##SUF; \
    const float th##SUF = (XC - icw##SUF) * ibr##SUF; \
    const float om##SUF = 1.0f - th##SUF; \
    const float tm##SUF = th##SUF * om##SUF; \
    const float num##SUF = ih##SUF * (idl##SUF * th##SUF * th##SUF + idv##SUF * tm##SUF); \
    const float den##SUF = idl##SUF + (idv##SUF + idvp##SUF - 2.0f * idl##SUF) * tm##SUF; \
    const float dr##SUF = rcp_fast(den##SUF); \
    const float dn##SUF = idl##SUF * idl##SUF * \
        (idvp##SUF * th##SUF * th##SUF + 2.0f * idl##SUF * tm##SUF + idv##SUF * om##SUF * om##SUF); \
    const float ld##SUF = LN2 * log2_fast(dn##SUF * dr##SUF * dr##SUF); \
    const bool in##SUF = (XF >= -Bc) && (XF <= Bc); \
    const float ZV = in##SUF ? (ich##SUF + num##SUF * dr##SUF) : XF; \
    float LV = in##SUF ? ld##SUF : 0.0f;

// ---------------- fully fused single kernel ----------------------------------
// grid (256, 8): x = 128-sample tile, y = 8-dim group (y==7 slot7 -> dim 0).
// causality: y<4 -> l<32 -> only k<32 contributes (W1 pre-masked) -> 1 MFMA.
__global__ __launch_bounds__(256, 4) void fused_kernel(
    const float* __restrict__ x, const float* __restrict__ init_param,
    const float* __restrict__ W1, const float* __restrict__ b1,
    const float* __restrict__ W2, const float* __restrict__ b2,
    const float* __restrict__ W3, const float* __restrict__ b3,
    float* __restrict__ out)
{
    __shared__ ushort h1c[128 * H1S];    // 18432 B
    __shared__ float  wl[8 * WSL];       // 6912 B
    __shared__ ushort Blds[64 * BS];     // 9216 B  -> total 34560 B, 4 blocks/CU
    const int tid = threadIdx.x;
    const int s0 = blockIdx.x * 128;
    const int y  = blockIdx.y;
    const int bx = blockIdx.x;
    const int lane = tid & 63;
    const int wave = __builtin_amdgcn_readfirstlane(tid >> 6);
    const int ln = lane & 15, qg = lane >> 4;
    const int l0 = y * 8;

    // spline x values for this wave's 2 dims x 2 sample-halves
    const int dA = y * 8 + 1 + 2 * wave;
    const int dB = (y == 7 && wave == 3) ? 0 : dA + 1;
    const float* xr0 = x + (size_t)(s0 + lane) * 64;
    const float* xr1 = xr0 + 64 * 64;
    float xA0 = xr0[dA], xA1 = xr1[dA];
    float xB0 = xr0[dB], xB1 = xr1[dB];

    // A-fragments for two m-tiles (rows wave*16 and 64+wave*16)
    short8 a0_0, a1_0, a0_1, a1_1;
    {
        const float* p0 = x + (size_t)(s0 + wave * 16 + ln) * 64 + qg * 8;
        const float* p1 = p0 + 64 * 64;
        a0_0 = pack_a(*(const f4*)p0, *(const f4*)(p0 + 4));
        a0_1 = pack_a(*(const f4*)p1, *(const f4*)(p1 + 4));
        if (y >= 4) {
            a1_0 = pack_a(*(const f4*)(p0 + 32), *(const f4*)(p0 + 36));
            a1_1 = pack_a(*(const f4*)(p1 + 32), *(const f4*)(p1 + 36));
        } else { a1_0 = a0_0; a1_1 = a0_1; }
    }

    // ---- stage B-tile from W1: Blds[n_local][k] bf16, n = y*64+n_local ----
    {
        const int n_local = tid >> 2;
        const int n = y * 64 + n_local;
        const int l = n >> 3, h = n & 7;
        const float* src = W1 + (size_t)l * 63 * 8 + h;   // + k*8 per k
        unsigned* drow = (unsigned*)&Blds[n_local * BS];
        if (y < 4) {
            const int kc0 = (tid & 3) * 8;
            #pragma unroll
            for (int j = 0; j < 4; ++j) {
                int k = kc0 + 2 * j;                      // k<32<63, n<256<504: no guards
                float v0 = src[(size_t)k * 8];
                float v1 = src[(size_t)(k + 1) * 8];
                drow[(kc0 >> 1) + j] = pack_bf16t2(v0, v1);
            }
        } else {
            const int kc0 = (tid & 3) * 16;
            #pragma unroll
            for (int j = 0; j < 8; ++j) {
                int k = kc0 + 2 * j;
                float v0 = (n < 504 && k < 63)     ? src[(size_t)k * 8]       : 0.f;
                float v1 = (n < 504 && k + 1 < 63) ? src[(size_t)(k + 1) * 8] : 0.f;
                drow[(kc0 >> 1) + j] = pack_bf16t2(v0, v1);
            }
        }
    }

    // ---- stage this block's 8 dims of weights into LDS (log2-domain scaled) ----
    if (tid < 128) {   // W2: 8 slots x 64 floats, f4, x 2log2e
        int s = tid >> 4, o = (tid & 15) * 4;
        if (l0 + s < LL)
            *(f4*)&wl[s * WSL + o] = splat4(TWOLOG2E) * (*(const f4*)&W2[(l0 + s) * 64 + o]);
    }
    if (tid < 64) {    // b2: 8 x 8, x 2log2e
        int s = tid >> 3, o = tid & 7;
        if (l0 + s < LL) wl[s * WSL + 64 + o] = TWOLOG2E * b2[(l0 + s) * 8 + o];
    }
    #pragma unroll
    for (int q0 = 0; q0 < 448; q0 += 256) {   // W3: 8 slots x 56 f2, x log2e
        int q = q0 + tid;
        if (q < 448) {
            int s = q / 56, r = q % 56, g = r / 7, o = r % 7;
            if (l0 + s < LL)
                *(f2*)&wl[s * WSL + 72 + g * 16 + o * 2] =
                    splat2(LOG2E) * (*(const f2*)&W3[(l0 + s) * 112 + g * 14 + o * 2]);
        }
    }
    if (tid < 64) {    // zero W3 pad cols 14,15
        int s = tid >> 3, g = tid & 7;
        *(f2*)&wl[s * WSL + 72 + g * 16 + 14] = splat2(0.f);
    }
    if (tid < 112) {   // b3: 8 x 14, x log2e
        int s = tid / 14, o = tid % 14;
        wl[s * WSL + 200 + o] = LOG2E * b3[(l0 + s < LL ? l0 + s : 0) * PP + o];
    }
    if (tid < 16) {    // zero b3 pad
        int s = tid >> 1, o = 214 + (tid & 1);
        wl[s * WSL + o] = 0.f;
    }
    __syncthreads();   // Blds + wl ready

    // ---- phase 1: MFMA 64 outcols x two 16-row m-tiles (B from LDS) ----
    #pragma unroll
    for (int nt = 0; nt < 4; ++nt) {
        int ncol = y * 64 + nt * 16 + ln;
        const ushort* brow = &Blds[(nt * 16 + ln) * BS + qg * 8];
        short8 bf0 = *(const short8*)brow;
        f32x4 acc0 = {0.f, 0.f, 0.f, 0.f};
        f32x4 acc1 = {0.f, 0.f, 0.f, 0.f};
        acc0 = __builtin_amdgcn_mfma_f32_16x16x32_bf16(a0_0, bf0, acc0, 0, 0, 0);
        acc1 = __builtin_amdgcn_mfma_f32_16x16x32_bf16(a0_1, bf0, acc1, 0, 0, 0);
        if (y >= 4) {
            short8 bf1 = *(const short8*)(brow + 32);
            acc0 = __builtin_amdgcn_mfma_f32_16x16x32_bf16(a1_0, bf1, acc0, 0, 0, 0);
            acc1 = __builtin_amdgcn_mfma_f32_16x16x32_bf16(a1_1, bf1, acc1, 0, 0, 0);
        }
        float bias2 = (ncol < 504) ? TWOLOG2E * b1[ncol] : 0.f;
        #pragma unroll
        for (int r = 0; r < 4; ++r) {
            int row = wave * 16 + qg * 4 + r;
            float v0 = tanh_pre(fmaf(TWOLOG2E, acc0[r], bias2));
            float v1 = tanh_pre(fmaf(TWOLOG2E, acc1[r], bias2));
            h1c[row * H1S + nt * 16 + ln] = to_bf16t(v0);
            h1c[(row + 64) * H1S + nt * 16 + ln] = to_bf16t(v1);
        }
    }
    __syncthreads();   // h1c ready

    // h1 fragments: 2 dims x 2 sample-halves
    const int slA = 2 * wave, slB = 2 * wave + 1;
    uint4 hA0 = *(const uint4*)&h1c[lane * H1S + slA * 8];
    uint4 hA1 = *(const uint4*)&h1c[(lane + 64) * H1S + slA * 8];
    uint4 hB0 = *(const uint4*)&h1c[lane * H1S + slB * 8];
    uint4 hB1 = *(const uint4*)&h1c[(lane + 64) * H1S + slB * 8];

    // ---- phase 2a: both MLPs -> 56 named p-scalars (log2 domain) ----
    float pA0_0, pA0_1, pA0_2, pA0_3, pA0_4, pA0_5, pA0_6, pA0_7;
    float pA0_8, pA0_9, pA0_10, pA0_11, pA0_12, pA0_13;
    float pA1_0, pA1_1, pA1_2, pA1_3, pA1_4, pA1_5, pA1_6, pA1_7;
    float pA1_8, pA1_9, pA1_10, pA1_11, pA1_12, pA1_13;
    float pB0_0, pB0_1, pB0_2, pB0_3, pB0_4, pB0_5, pB0_6, pB0_7;
    float pB0_8, pB0_9, pB0_10, pB0_11, pB0_12, pB0_13;
    float pB1_0, pB1_1, pB1_2, pB1_3, pB1_4, pB1_5, pB1_6, pB1_7;
    float pB1_8, pB1_9, pB1_10, pB1_11, pB1_12, pB1_13;
    MLP_BLOCK(A, wl + slA * WSL, hA0, hA1)
    MLP_BLOCK(B, wl + slB * WSL, hB0, hB1)

    if (dB == 0) {   // wave-uniform override (y==7, wave==3); log2 domain
        pB0_0 = LOG2E * init_param[0];  pB0_1 = LOG2E * init_param[1];
        pB0_2 = LOG2E * init_param[2];  pB0_3 = LOG2E * init_param[3];
        pB0_4 = LOG2E * init_param[4];  pB0_5 = LOG2E * init_param[5];
        pB0_6 = LOG2E * init_param[6];  pB0_7 = LOG2E * init_param[7];
        pB0_8 = LOG2E * init_param[8];  pB0_9 = LOG2E * init_param[9];
        pB0_10 = LOG2E * init_param[10]; pB0_11 = LOG2E * init_param[11];
        pB0_12 = LOG2E * init_param[12]; pB0_13 = LOG2E * init_param[13];
        pB1_0 = pB0_0;  pB1_1 = pB0_1;  pB1_2 = pB0_2;  pB1_3 = pB0_3;
        pB1_4 = pB0_4;  pB1_5 = pB0_5;  pB1_6 = pB0_6;  pB1_7 = pB0_7;
        pB1_8 = pB0_8;  pB1_9 = pB0_9;  pB1_10 = pB0_10; pB1_11 = pB0_11;
        pB1_12 = pB0_12; pB1_13 = pB0_13;
    }

    // ---- phase 2b: spline, 4 chains (A0,A1,B0,B1), all-scalar state ----
    const f4 minv = {MIN_Wc, MIN_Hc, MIN_Wc, MIN_Hc};
    EPACK(A)
    EPACK(B)

    const float xcA0 = fminf(fmaxf(xA0, -Bc), Bc);
    const float xcA1 = fminf(fmaxf(xA1, -Bc), Bc);
    const float xcB0 = fminf(fmaxf(xB0, -Bc), Bc);
    const float xcB1 = fminf(fmaxf(xB1, -Bc), Bc);

    CASCADE(A0, A, x, y, pA0_10, pA0_11, pA0_12, pA0_13, xcA0)
    CASCADE(A1, A, z, w, pA1_10, pA1_11, pA1_12, pA1_13, xcA1)
    CASCADE(B0, B, x, y, pB0_10, pB0_11, pB0_12, pB0_13, xcB0)
    CASCADE(B1, B, z, w, pB1_10, pB1_11, pB1_12, pB1_13, xcB1)

    CHAIN_FIN(A0, xcA0, xA0, z0, l0v)
    CHAIN_FIN(A1, xcA1, xA1, z1, l1v)
    CHAIN_FIN(B0, xcB0, xB0, z2, l2v)
    CHAIN_FIN(B1, xcB1, xB1, z3, l3v)

    out[dA * NN + s0 + lane]      = z0;   // coalesced
    out[dA * NN + s0 + 64 + lane] = z1;
    out[dB * NN + s0 + lane]      = z2;
    out[dB * NN + s0 + 64 + lane] = z3;

    #pragma unroll
    for (int off = 32; off > 0; off >>= 1) {
        l0v += __shfl_down(l0v, off);
        l1v += __shfl_down(l1v, off);
        l2v += __shfl_down(l2v, off);
        l3v += __shfl_down(l3v, off);
    }
    if (lane == 0) {
        float* lo = out + NN * DD;
        lo[dA * (NN / 64) + 2 * bx]     = l0v;
        lo[dA * (NN / 64) + 2 * bx + 1] = l1v;
        lo[dB * (NN / 64) + 2 * bx]     = l2v;
        lo[dB * (NN / 64) + 2 * bx + 1] = l3v;
    }
}

extern "C" void kernel_launch(void* const* d_in, const int* in_sizes, int n_in,
                              void* d_out, int out_size, void* d_ws, size_t ws_size,
                              hipStream_t stream) {
    const float* x          = (const float*)d_in[0];
    const float* init_param = (const float*)d_in[1];
    const float* W1         = (const float*)d_in[2];
    const float* b1         = (const float*)d_in[3];
    const float* W2         = (const float*)d_in[4];
    const float* b2         = (const float*)d_in[5];
    const float* W3         = (const float*)d_in[6];
    const float* b3         = (const float*)d_in[7];
    float* out = (float*)d_out;

    // single launch; d_ws unused
    fused_kernel<<<dim3(256, 8), 256, 0, stream>>>(x, init_param, W1, b1,
                                                   W2, b2, W3, b3, out);
}